// Round 1
// baseline (299.659 us; speedup 1.0000x reference)
//
#include <hip/hip_runtime.h>
#include <math.h>

#define BATCH 32768
#define NCLS  2048
#define BLOCK 256

// Main kernel: one thread per row for the cheap (t != 0) path.
// Rows with t == 0 are collected into an LDS list and processed
// block-cooperatively (full-row exp-sum) afterwards.
__global__ __launch_bounds__(BLOCK) void mpl_main(const float* __restrict__ x,
                                                  const int* __restrict__ tgt,
                                                  float* __restrict__ acc) {
    __shared__ int   zlist[BLOCK];
    __shared__ int   zcnt;
    __shared__ float red[BLOCK / 64];

    if (threadIdx.x == 0) zcnt = 0;
    __syncthreads();

    const int row = blockIdx.x * BLOCK + threadIdx.x;  // BATCH % BLOCK == 0
    const int t = tgt[row];

    float li = 0.0f;
    if (t != 0) {
        // negative set = {class 0}; loss = log(e^{x0} + e^{xt}) - xt = log1p(e^{x0-xt})
        const float x0 = x[(size_t)row * NCLS];
        const float xt = x[(size_t)row * NCLS + t];
        li = log1pf(expf(x0 - xt));
    } else {
        zlist[atomicAdd(&zcnt, 1)] = row;
    }

    // block-reduce the cheap-path losses
    #pragma unroll
    for (int o = 32; o > 0; o >>= 1) li += __shfl_down(li, o, 64);
    const int lane = threadIdx.x & 63;
    const int wv   = threadIdx.x >> 6;
    if (lane == 0) red[wv] = li;
    __syncthreads();

    float block_sum = 0.0f;
    if (threadIdx.x == 0) {
        #pragma unroll
        for (int w = 0; w < BLOCK / 64; ++w) block_sum += red[w];
    }
    __syncthreads();  // red[] about to be reused

    // expensive path: full-row sum of exp for each t == 0 row (rare)
    const int n = zcnt;
    for (int k = 0; k < n; ++k) {
        const int zr = zlist[k];
        const float4* xr = (const float4*)(x + (size_t)zr * NCLS);
        float s = 0.0f;
        #pragma unroll
        for (int j = threadIdx.x; j < NCLS / 4; j += BLOCK) {
            const float4 v = xr[j];
            s += expf(v.x) + expf(v.y) + expf(v.z) + expf(v.w);
        }
        #pragma unroll
        for (int o = 32; o > 0; o >>= 1) s += __shfl_down(s, o, 64);
        if (lane == 0) red[wv] = s;
        __syncthreads();
        if (threadIdx.x == 0) {
            float tot = 0.0f;
            #pragma unroll
            for (int w = 0; w < BLOCK / 64; ++w) tot += red[w];
            // loss = log(neg_sum + e^{x0}) - x0 = log(full_sum) - x0
            const float x0 = x[(size_t)zr * NCLS];
            block_sum += logf(tot) - x0;
        }
        __syncthreads();  // red[] reuse next iteration
    }

    if (threadIdx.x == 0) atomicAdd(acc, block_sum);
}

__global__ void mpl_finalize(const float* __restrict__ acc, float* __restrict__ out) {
    out[0] = acc[0] * (1.0f / (float)BATCH);
}

extern "C" void kernel_launch(void* const* d_in, const int* in_sizes, int n_in,
                              void* d_out, int out_size, void* d_ws, size_t ws_size,
                              hipStream_t stream) {
    const float* x   = (const float*)d_in[0];
    const int*   tgt = (const int*)d_in[1];
    float* out = (float*)d_out;
    float* acc = (float*)d_ws;

    hipMemsetAsync(acc, 0, sizeof(float), stream);
    mpl_main<<<BATCH / BLOCK, BLOCK, 0, stream>>>(x, tgt, acc);
    mpl_finalize<<<1, 1, 0, stream>>>(acc, out);
}